// Round 8
// baseline (274.001 us; speedup 1.0000x reference)
//
#include <hip/hip_runtime.h>

#define NBATCH 32
#define NDIM 512
#define NFAST 448
#define NPAIR 224
#define NWAVE 8

// ---- DPP cross-lane primitives (VALU-speed; no LDS, no barriers) ----

template <int CTRL, int RMASK>
__device__ __forceinline__ float dpp_add(float x) {
  int t = __builtin_amdgcn_update_dpp(0, __float_as_int(x), CTRL, RMASK, 0xf,
                                      false);
  return x + __int_as_float(t);
}

// wave64 inclusive prefix sum
__device__ __forceinline__ float prefix_inc(float x) {
  x = dpp_add<0x111, 0xf>(x);  // row_shr:1
  x = dpp_add<0x112, 0xf>(x);  // row_shr:2
  x = dpp_add<0x114, 0xf>(x);  // row_shr:4
  x = dpp_add<0x118, 0xf>(x);  // row_shr:8
  x = dpp_add<0x142, 0xa>(x);  // row_bcast:15 -> rows 1,3
  x = dpp_add<0x143, 0xc>(x);  // row_bcast:31 -> rows 2,3
  return x;
}

// shift one lane up (lane i gets lane i-1); lane 0 receives `fill`
__device__ __forceinline__ float wave_shr1(float x, float fill) {
  return __int_as_float(__builtin_amdgcn_update_dpp(
      __float_as_int(fill), __float_as_int(x), 0x138 /*wave_shr:1*/, 0xf, 0xf,
      false));
}

// one step of the wave64 inclusive affine-composition scan.
// Compose earlier-then-later: B = A*Be + B ; A = A*Ae. Identity = (1,0).
template <int CTRL, int RMASK>
__device__ __forceinline__ void aff_step(float& A, float& B) {
  float Ae = __int_as_float(__builtin_amdgcn_update_dpp(
      __float_as_int(1.0f), __float_as_int(A), CTRL, RMASK, 0xf, false));
  float Be = __int_as_float(__builtin_amdgcn_update_dpp(
      0, __float_as_int(B), CTRL, RMASK, 0xf, false));
  B = fmaf(A, Be, B);
  A = A * Ae;
}

// Workgroup barrier WITHOUT the vmcnt(0) drain __syncthreads() emits.
// Writer-side LDS ordering via lgkmcnt(0); trailing empty asm with a
// memory clobber stops the compiler hoisting post-barrier LDS reads.
// Global prefetch loads stay in flight across group barriers.
__device__ __forceinline__ void wg_barrier() {
  asm volatile("s_waitcnt lgkmcnt(0)" ::: "memory");
  __builtin_amdgcn_s_barrier();
  asm volatile("" ::: "memory");
}

// R21: R20's pair systolic (PROVEN math, verbatim here) with EPOCH
// barriers: skew deepened to 3 pair-steps (wave w does pair s at
// t = s + 3w) and ONE barrier per 3 pair-steps (6 rows). A record
// written at step T is read at T+3; exactly one group barrier lies in
// (T, T+3], and its lgkmcnt(0) orders the ds_write -> visibility proof
// intact. Between barriers waves free-run, so a wave stalled on its
// DPP scan chain is covered by its SIMD-mate (which is no longer
// parked at a per-step barrier). Barrier count 231 -> 82. Per-row math
// and composition order identical to R20 => absmax unchanged.
__global__ __launch_bounds__(512, 2)
void sb_kernel(const float* __restrict__ x, const float* __restrict__ xm,
               float* __restrict__ out) {
  const int tid = (int)threadIdx.x;
  const int lane = tid & 63;
  const int w = __builtin_amdgcn_readfirstlane(tid >> 6);  // wave id 0..7
  const int w3 = 3 * w;                                    // skew in steps
  const size_t base =
      (size_t)blockIdx.x * NDIM * NDIM + (size_t)(w * 64 + lane);
  const float* xb = x + base;
  const float* mb = xm + base;
  float* ob = out + base;

  __shared__ float4 recs[NFAST];              // rolling cum {A,B,cumPA,-}
  __shared__ alignas(16) float ex_sa[NWAVE];  // FULL-mode exchange
  __shared__ alignas(16) float ex_S[NWAVE];
  __shared__ alignas(16) float ex_A[NWAVE];
  __shared__ alignas(16) float ex_B[NWAVE];

  // per-lane state
  float w8, t8;                    // stick remainder + next-row scan input
  float c2_0, oc2_0, c2_1, oc2_1;  // current pair's constants (2 rows)
  float c1, c2, oc2;               // FULL-phase per-row constants
  float fu = 0.0f, S = 0.0f;

  // ---- prologue: rows 0,1 direct; pair1(rows2,3) -> slot1, pair2
  // (rows4,5) -> slot2 for ALL waves (every wave starts at unroll
  // position k=0 under the 3-step skew). Slot discipline: at unroll pos
  // k a wave writes pair s+3 into slot[k] and preps pair s+1 from
  // slot[(k+1)%3]; write->read distance is 2 steps. ----
  float X0 = xb[0], M0 = mb[0];
  float X1 = xb[NDIM], M1 = mb[NDIM];
  float Bx0 = xb[2 * NDIM], Bx1 = xb[3 * NDIM];  // slot 1 = pair 1
  float Bm0 = mb[2 * NDIM], Bm1 = mb[3 * NDIM];
  float Cx0 = xb[4 * NDIM], Cx1 = xb[5 * NDIM];  // slot 2 = pair 2
  float Cm0 = mb[4 * NDIM], Cm1 = mb[5 * NDIM];
  float Ax0 = Bx0, Ax1 = Bx1, Am0 = Bm0, Am1 = Bm1;  // slot 0 (dead init)

  {  // prep rows 0,1 constants; row-0 scan input (w8 == 1)
    float sg0 = __builtin_amdgcn_rcpf(1.0f + __expf(-X0));
    c2_0 = M0 * sg0;
    oc2_0 = 1.0f - c2_0;
    float sg1 = __builtin_amdgcn_rcpf(1.0f + __expf(-X1));
    c2_1 = M1 * sg1;
    oc2_1 = 1.0f - c2_1;
    w8 = 1.0f;
    t8 = c2_0;
  }

  // running pointers (strength-reduced; advance unconditionally per
  // group, so inactive waves just carry out-of-window values that are
  // never dereferenced). At the wave's first active group (g = w):
  // load rows 6,7 / store row 0.
  const float* px = xb + (long)(6 - 6 * w) * NDIM;
  const float* pm = mb + (long)(6 - 6 * w) * NDIM;
  float* po = ob - (long)(6 * w) * NDIM;

  // ---- one row of proven math (guess scan + affine scan) ----
  auto row_fast = [&](int m, const float4& r, float c2r, float oc2r,
                      float* pO) {
    float PA = prefix_inc(t8);
    float uin = fmaxf(1.0f - (r.z + (PA - t8)), 0.0f);
    bool pW = w8 < uin;
    float A = pW ? 1.0f : oc2r;
    float Bv = pW ? (-t8) : 0.0f;
    aff_step<0x111, 0xf>(A, Bv);
    aff_step<0x112, 0xf>(A, Bv);
    aff_step<0x114, 0xf>(A, Bv);
    aff_step<0x118, 0xf>(A, Bv);
    aff_step<0x142, 0xa>(A, Bv);
    aff_step<0x143, 0xc>(A, Bv);
    float Aex = wave_shr1(A, 1.0f);
    float Bex = wave_shr1(Bv, 0.0f);
    if (w < NWAVE - 1 && lane == 63)
      recs[m] = make_float4(A * r.x, fmaf(A, r.y, Bv), r.z + PA, 0.0f);
    float E = r.x + r.y;
    float e = fminf(fmaxf(fmaf(Aex, E, Bex), 0.0f), 1.0f);
    float p = c2r * fminf(e, w8);
    w8 -= p;
    *pO = p;
  };

  // ---- 2-row systolic step (NO barrier here; barrier per group) ----
  auto pair_step = [&](int t, int k, float& WX0, float& WX1, float& WM0,
                       float& WM1, const float& RX0, const float& RX1,
                       const float& RM0, const float& RM1) {
    const int s = t - w3;
    if ((unsigned)s < (unsigned)NPAIR) {  // wave-uniform
      const int m = 2 * s;
      // read both predecessor cum records (published >= 3 steps ago,
      // across >= 1 group barrier)
      float4 r0 = make_float4(1.0f, 0.0f, 0.0f, 0.0f), r1 = r0;
      if (w > 0) {
        r0 = recs[m];
        r1 = recs[m + 1];
      }
      // issue next pair's global loads directly into slot registers
      const float* pxk = px + (size_t)(2 * k) * NDIM;
      const float* pmk = pm + (size_t)(2 * k) * NDIM;
      WX0 = pxk[0];
      WX1 = pxk[NDIM];
      WM0 = pmk[0];
      WM1 = pmk[NDIM];

      // prep pair s+1 (data loaded 2 steps ago; off-chain)
      float sg0 = __builtin_amdgcn_rcpf(1.0f + __expf(-RX0));
      float c2n0 = RM0 * sg0;
      float oc2n0 = 1.0f - c2n0;
      float sg1 = __builtin_amdgcn_rcpf(1.0f + __expf(-RX1));
      float c2n1 = RM1 * sg1;
      float oc2n1 = 1.0f - c2n1;

      float* pok = po + (size_t)(2 * k) * NDIM;
      // row 2s
      row_fast(m, r0, c2_0, oc2_0, pok);
      t8 = c2_1 * w8;
      // row 2s+1
      row_fast(m + 1, r1, c2_1, oc2_1, pok + NDIM);
      // next pair's scan input + constants
      t8 = c2n0 * w8;
      c2_0 = c2n0;
      oc2_0 = oc2n0;
      c2_1 = c2n1;
      oc2_1 = oc2n1;
    }
  };

  // fast phase: steps t = 0 .. 244 (wave w active for t in [3w, 3w+224));
  // one barrier per 3-step group.
#pragma unroll 1
  for (int t = 0; t < NPAIR + 3 * (NWAVE - 1); t += 3) {
    pair_step(t + 0, 0, Ax0, Ax1, Am0, Am1, Bx0, Bx1, Bm0, Bm1);
    pair_step(t + 1, 1, Bx0, Bx1, Bm0, Bm1, Cx0, Cx1, Cm0, Cm1);
    pair_step(t + 2, 2, Cx0, Cx1, Cm0, Cm1, Ax0, Ax1, Am0, Am1);
    wg_barrier();
    px += 6 * NDIM;
    pm += 6 * NDIM;
    po += 6 * NDIM;
  }
  // all waves synced by the final group barrier; recs no longer used.
  // c2_0/oc2_0 now hold row-448 constants (prepped at s=223).

  // ---- bridge: row-448 constants + fu/S; reload rows 449..451 into
  // FULL-phase single-row slots (L2-hot, one-time). t8 already =
  // c2(448) * w8 from the last fast step. ----
  float fx0, fm0, fx1, fm1, fx2, fm2, fx3, fm3;
  {
    float m448 = mb[(size_t)448 * NDIM];
    fx1 = xb[(size_t)449 * NDIM];
    fm1 = mb[(size_t)449 * NDIM];
    fx2 = xb[(size_t)450 * NDIM];
    fm2 = mb[(size_t)450 * NDIM];
    fx3 = xb[(size_t)451 * NDIM];
    fm3 = mb[(size_t)451 * NDIM];
    fx0 = fx1;  // defined; overwritten at m=448 step
    fm0 = fm1;
    c2 = c2_0;
    oc2 = oc2_0;
    c1 = m448 - c2;
    float om = 1.0f - m448;
    fu = fmaxf(w8 - om, 0.0f);
    S = fu;
  }

  // ---- FULL row body: proven 2-barrier exchange (backward dep on S) ----
  auto row_full = [&](int m, float& WX, float& WM, const float& RX,
                      const float& RM) {
    const size_t nro = (size_t)((m + 4) & (NDIM - 1)) * NDIM;
    WX = xb[nro];
    WM = mb[nro];

    // local wave scans (chain head)
    float PS = prefix_inc(S);
    float PA = prefix_inc(t8);

    if (lane == 63) {
      ex_sa[w] = PA;  // wave-inclusive totals
      ex_S[w] = PS;
    }
    wg_barrier();  // bar1: publish scan totals

    float4 sl = *(const float4*)&ex_sa[0];
    float4 sh = *(const float4*)&ex_sa[4];
    float4 Sl = *(const float4*)&ex_S[0];
    float4 Sh = *(const float4*)&ex_S[4];
    float off_sa = 0.0f, off_S = 0.0f;
    if (w > 0) { off_sa += sl.x; off_S += Sl.x; }
    if (w > 1) { off_sa += sl.y; off_S += Sl.y; }
    if (w > 2) { off_sa += sl.z; off_S += Sl.z; }
    if (w > 3) { off_sa += sl.w; off_S += Sl.w; }
    if (w > 4) { off_sa += sh.x; off_S += Sh.x; }
    if (w > 5) { off_sa += sh.y; off_S += Sh.y; }
    if (w > 6) { off_sa += sh.z; off_S += Sh.z; }
    float Tg =
        ((Sl.x + Sl.y) + (Sl.z + Sl.w)) + ((Sh.x + Sh.y) + (Sh.z + Sh.w));

    float uin = fmaxf(1.0f - (off_sa + (PA - t8)), 0.0f);
    float R_ = (Tg - off_S) - PS;  // future mass strictly after this lane
    float nc1m = -c1 * R_;         // per-lane suf == 0 at 1 col/lane

    // branch prediction (1 cell)
    bool pW = w8 < uin;
    float aP = pW ? 1.0f : oc2;
    float bP = pW ? (-t8) : 0.0f;
    bool pL = (uin - R_) > 0.0f;
    if (pL) {
      aP -= c1;
      bP -= nc1m;
    }

    // wave affine scan
    float A = aP, Bv = bP;
    aff_step<0x111, 0xf>(A, Bv);
    aff_step<0x112, 0xf>(A, Bv);
    aff_step<0x114, 0xf>(A, Bv);
    aff_step<0x118, 0xf>(A, Bv);
    aff_step<0x142, 0xa>(A, Bv);
    aff_step<0x143, 0xc>(A, Bv);
    float Aex = wave_shr1(A, 1.0f);
    float Bex = wave_shr1(Bv, 0.0f);

    if (lane == 63) {
      ex_A[w] = A;  // wave-inclusive composition
      ex_B[w] = Bv;
    }
    wg_barrier();  // bar2: publish affine totals

    float4 Al = *(const float4*)&ex_A[0];
    float4 Ah = *(const float4*)&ex_A[4];
    float4 Bl = *(const float4*)&ex_B[0];
    float4 Bh = *(const float4*)&ex_B[4];
    float E = 1.0f;
    if (w > 0) E = fmaf(Al.x, E, Bl.x);
    if (w > 1) E = fmaf(Al.y, E, Bl.y);
    if (w > 2) E = fmaf(Al.z, E, Bl.z);
    if (w > 3) E = fmaf(Al.w, E, Bl.w);
    if (w > 4) E = fmaf(Ah.x, E, Bh.x);
    if (w > 5) E = fmaf(Ah.y, E, Bh.y);
    if (w > 6) E = fmaf(Ah.z, E, Bh.z);
    float e = fminf(fmaxf(fmaf(Aex, E, Bex), 0.0f), 1.0f);  // lane entry

    // row m+1 x-only prep (off-chain)
    float sg = __builtin_amdgcn_rcpf(1.0f + __expf(-RX));
    float c2n = RM * sg;
    float oc2n = 1.0f - c2n;
    float c1n = RM - c2n;
    float omn = 1.0f - RM;

    // TRUE-branch output
    float U = fminf(e, w8);
    float g = fmaxf(fmaf(c1, e, nc1m), 0.0f);
    float p = fmaf(c2, U, g);
    w8 -= p;
    ob[(size_t)m * NDIM] = p;

    // next row's scan inputs
    t8 = c2n * w8;
    fu = fmaxf(w8 - omn, 0.0f);
    S = fu;
    c2 = c2n;
    oc2 = oc2n;
    c1 = c1n;
  };

#pragma unroll 1
  for (int m = NFAST; m < NDIM; m += 4) {
    row_full(m + 0, fx0, fm0, fx1, fm1);
    row_full(m + 1, fx1, fm1, fx2, fm2);
    row_full(m + 2, fx2, fm2, fx3, fm3);
    row_full(m + 3, fx3, fm3, fx0, fm0);
  }
}

extern "C" void kernel_launch(void* const* d_in, const int* in_sizes, int n_in,
                              void* d_out, int out_size, void* d_ws,
                              size_t ws_size, hipStream_t stream) {
  const float* x = (const float*)d_in[0];
  const float* xmask = (const float*)d_in[1];
  float* out = (float*)d_out;
  (void)in_sizes;
  (void)n_in;
  (void)out_size;
  (void)d_ws;
  (void)ws_size;
  hipLaunchKernelGGL(sb_kernel, dim3(NBATCH), dim3(512), 0, stream, x, xmask,
                     out);
}

// Round 9
// 250.458 us; speedup vs baseline: 1.0940x; 1.0940x over previous
//
#include <hip/hip_runtime.h>

#define NBATCH 32
#define NDIM 512
#define NFAST 448
#define NPAIR 224
#define NWAVE 8

// ---- DPP cross-lane primitives ----
// Native DPP-arithmetic forms (gfx9 idiom): one instruction per scan
// stage instead of the builtin's mov + mov_dpp + op triple. Invalid
// source lanes (bound_ctrl omitted => don't write) keep their value,
// which is exactly the scan identity. s_nop's cover the GFX9
// VALU-write -> DPP-read hazard (2 wait states), which the compiler
// cannot see across inline-asm boundaries. Results are bit-identical
// to the previous builtin implementation.

// wave64 inclusive prefix sum (6 x v_add_f32_dpp)
__device__ __forceinline__ float prefix_inc(float x) {
  asm("s_nop 1\n\t"
      "v_add_f32_dpp %0, %0, %0 row_shr:1 row_mask:0xf bank_mask:0xf\n\t"
      "s_nop 1\n\t"
      "v_add_f32_dpp %0, %0, %0 row_shr:2 row_mask:0xf bank_mask:0xf\n\t"
      "s_nop 1\n\t"
      "v_add_f32_dpp %0, %0, %0 row_shr:4 row_mask:0xf bank_mask:0xf\n\t"
      "s_nop 1\n\t"
      "v_add_f32_dpp %0, %0, %0 row_shr:8 row_mask:0xf bank_mask:0xf\n\t"
      "s_nop 1\n\t"
      "v_add_f32_dpp %0, %0, %0 row_bcast:15 row_mask:0xa bank_mask:0xf\n\t"
      "s_nop 1\n\t"
      "v_add_f32_dpp %0, %0, %0 row_bcast:31 row_mask:0xc bank_mask:0xf\n\t"
      "s_nop 1"
      : "+v"(x));
  return x;
}

// wave64 inclusive affine-composition scan: per stage
//   B += dpp(B) * A   (v_fmac, uses pre-update A == fmaf(A, Be, B))
//   A *= dpp(A)       (v_mul)
// Skipped invalid lanes == compose with identity (1,0). 12 instructions.
__device__ __forceinline__ void aff_scan(float& A, float& B) {
  asm("s_nop 1\n\t"
      "v_fmac_f32_dpp %1, %1, %0 row_shr:1 row_mask:0xf bank_mask:0xf\n\t"
      "v_mul_f32_dpp  %0, %0, %0 row_shr:1 row_mask:0xf bank_mask:0xf\n\t"
      "s_nop 0\n\t"
      "v_fmac_f32_dpp %1, %1, %0 row_shr:2 row_mask:0xf bank_mask:0xf\n\t"
      "v_mul_f32_dpp  %0, %0, %0 row_shr:2 row_mask:0xf bank_mask:0xf\n\t"
      "s_nop 0\n\t"
      "v_fmac_f32_dpp %1, %1, %0 row_shr:4 row_mask:0xf bank_mask:0xf\n\t"
      "v_mul_f32_dpp  %0, %0, %0 row_shr:4 row_mask:0xf bank_mask:0xf\n\t"
      "s_nop 0\n\t"
      "v_fmac_f32_dpp %1, %1, %0 row_shr:8 row_mask:0xf bank_mask:0xf\n\t"
      "v_mul_f32_dpp  %0, %0, %0 row_shr:8 row_mask:0xf bank_mask:0xf\n\t"
      "s_nop 0\n\t"
      "v_fmac_f32_dpp %1, %1, %0 row_bcast:15 row_mask:0xa bank_mask:0xf\n\t"
      "v_mul_f32_dpp  %0, %0, %0 row_bcast:15 row_mask:0xa bank_mask:0xf\n\t"
      "s_nop 0\n\t"
      "v_fmac_f32_dpp %1, %1, %0 row_bcast:31 row_mask:0xc bank_mask:0xf\n\t"
      "v_mul_f32_dpp  %0, %0, %0 row_bcast:31 row_mask:0xc bank_mask:0xf\n\t"
      "s_nop 1"
      : "+v"(A), "+v"(B));
}

// shift one lane up (lane i gets lane i-1); lane 0 receives `fill`
__device__ __forceinline__ float wave_shr1(float x, float fill) {
  return __int_as_float(__builtin_amdgcn_update_dpp(
      __float_as_int(fill), __float_as_int(x), 0x138 /*wave_shr:1*/, 0xf, 0xf,
      false));
}

// Workgroup barrier WITHOUT the vmcnt(0) drain __syncthreads() emits.
// Writer-side LDS ordering via lgkmcnt(0); trailing empty asm with a
// memory clobber stops the compiler hoisting post-barrier LDS reads.
// Global prefetch loads stay in flight across group barriers.
__device__ __forceinline__ void wg_barrier() {
  asm volatile("s_waitcnt lgkmcnt(0)" ::: "memory");
  __builtin_amdgcn_s_barrier();
  asm volatile("" ::: "memory");
}

// R22: R21's epoch-barrier pair systolic (PROVEN math, verbatim order)
// with the DPP scans re-expressed as native DPP-arithmetic instructions
// (v_add_f32_dpp / v_fmac_f32_dpp / v_mul_f32_dpp): scan cost per row
// drops from ~58 to ~22 VALU ops, attacking the measured issue-bound
// regime (active-CU VALUBusy ~70%). Wave w owns cols [64w,64w+64), lane
// owns 1 col; wave w does pair s at step t = s + 3w; one barrier per 3
// pair-steps (record written at T is read at T+3, one barrier in
// (T,T+3] orders it). Math bit-identical to R20/R21 => absmax
// unchanged.
__global__ __launch_bounds__(512, 2)
void sb_kernel(const float* __restrict__ x, const float* __restrict__ xm,
               float* __restrict__ out) {
  const int tid = (int)threadIdx.x;
  const int lane = tid & 63;
  const int w = __builtin_amdgcn_readfirstlane(tid >> 6);  // wave id 0..7
  const int w3 = 3 * w;                                    // skew in steps
  const size_t base =
      (size_t)blockIdx.x * NDIM * NDIM + (size_t)(w * 64 + lane);
  const float* xb = x + base;
  const float* mb = xm + base;
  float* ob = out + base;

  __shared__ float4 recs[NFAST];              // rolling cum {A,B,cumPA,-}
  __shared__ alignas(16) float ex_sa[NWAVE];  // FULL-mode exchange
  __shared__ alignas(16) float ex_S[NWAVE];
  __shared__ alignas(16) float ex_A[NWAVE];
  __shared__ alignas(16) float ex_B[NWAVE];

  // per-lane state
  float w8, t8;                    // stick remainder + next-row scan input
  float c2_0, oc2_0, c2_1, oc2_1;  // current pair's constants (2 rows)
  float c1, c2, oc2;               // FULL-phase per-row constants
  float fu = 0.0f, S = 0.0f;

  // ---- prologue: rows 0,1 direct; pair1(rows2,3) -> slot1, pair2
  // (rows4,5) -> slot2 for ALL waves (every wave starts at unroll
  // position k=0 under the 3-step skew). Slot discipline: at unroll pos
  // k a wave writes pair s+3 into slot[k] and preps pair s+1 from
  // slot[(k+1)%3]; write->read distance is 2 steps. ----
  float X0 = xb[0], M0 = mb[0];
  float X1 = xb[NDIM], M1 = mb[NDIM];
  float Bx0 = xb[2 * NDIM], Bx1 = xb[3 * NDIM];  // slot 1 = pair 1
  float Bm0 = mb[2 * NDIM], Bm1 = mb[3 * NDIM];
  float Cx0 = xb[4 * NDIM], Cx1 = xb[5 * NDIM];  // slot 2 = pair 2
  float Cm0 = mb[4 * NDIM], Cm1 = mb[5 * NDIM];
  float Ax0 = Bx0, Ax1 = Bx1, Am0 = Bm0, Am1 = Bm1;  // slot 0 (dead init)

  {  // prep rows 0,1 constants; row-0 scan input (w8 == 1)
    float sg0 = __builtin_amdgcn_rcpf(1.0f + __expf(-X0));
    c2_0 = M0 * sg0;
    oc2_0 = 1.0f - c2_0;
    float sg1 = __builtin_amdgcn_rcpf(1.0f + __expf(-X1));
    c2_1 = M1 * sg1;
    oc2_1 = 1.0f - c2_1;
    w8 = 1.0f;
    t8 = c2_0;
  }

  // running pointers (strength-reduced; advance unconditionally per
  // group, so inactive waves just carry out-of-window values that are
  // never dereferenced). At the wave's first active group (g = w):
  // load rows 6,7 / store row 0.
  const float* px = xb + (long)(6 - 6 * w) * NDIM;
  const float* pm = mb + (long)(6 - 6 * w) * NDIM;
  float* po = ob - (long)(6 * w) * NDIM;

  // ---- one row of proven math (guess scan + affine scan) ----
  auto row_fast = [&](int m, const float4& r, float c2r, float oc2r,
                      float* pO) {
    float PA = prefix_inc(t8);
    float uin = fmaxf(1.0f - (r.z + (PA - t8)), 0.0f);
    bool pW = w8 < uin;
    float A = pW ? 1.0f : oc2r;
    float Bv = pW ? (-t8) : 0.0f;
    aff_scan(A, Bv);
    float Aex = wave_shr1(A, 1.0f);
    float Bex = wave_shr1(Bv, 0.0f);
    if (w < NWAVE - 1 && lane == 63)
      recs[m] = make_float4(A * r.x, fmaf(A, r.y, Bv), r.z + PA, 0.0f);
    float E = r.x + r.y;
    float e = fminf(fmaxf(fmaf(Aex, E, Bex), 0.0f), 1.0f);
    float p = c2r * fminf(e, w8);
    w8 -= p;
    *pO = p;
  };

  // ---- 2-row systolic step (NO barrier here; barrier per group) ----
  auto pair_step = [&](int t, int k, float& WX0, float& WX1, float& WM0,
                       float& WM1, const float& RX0, const float& RX1,
                       const float& RM0, const float& RM1) {
    const int s = t - w3;
    if ((unsigned)s < (unsigned)NPAIR) {  // wave-uniform
      const int m = 2 * s;
      // read both predecessor cum records (published >= 3 steps ago,
      // across >= 1 group barrier)
      float4 r0 = make_float4(1.0f, 0.0f, 0.0f, 0.0f), r1 = r0;
      if (w > 0) {
        r0 = recs[m];
        r1 = recs[m + 1];
      }
      // issue next pair's global loads directly into slot registers
      const float* pxk = px + (size_t)(2 * k) * NDIM;
      const float* pmk = pm + (size_t)(2 * k) * NDIM;
      WX0 = pxk[0];
      WX1 = pxk[NDIM];
      WM0 = pmk[0];
      WM1 = pmk[NDIM];

      // prep pair s+1 (data loaded 2 steps ago; off-chain)
      float sg0 = __builtin_amdgcn_rcpf(1.0f + __expf(-RX0));
      float c2n0 = RM0 * sg0;
      float oc2n0 = 1.0f - c2n0;
      float sg1 = __builtin_amdgcn_rcpf(1.0f + __expf(-RX1));
      float c2n1 = RM1 * sg1;
      float oc2n1 = 1.0f - c2n1;

      float* pok = po + (size_t)(2 * k) * NDIM;
      // row 2s
      row_fast(m, r0, c2_0, oc2_0, pok);
      t8 = c2_1 * w8;
      // row 2s+1
      row_fast(m + 1, r1, c2_1, oc2_1, pok + NDIM);
      // next pair's scan input + constants
      t8 = c2n0 * w8;
      c2_0 = c2n0;
      oc2_0 = oc2n0;
      c2_1 = c2n1;
      oc2_1 = oc2n1;
    }
  };

  // fast phase: steps t = 0 .. 244 (wave w active for t in [3w, 3w+224));
  // one barrier per 3-step group.
#pragma unroll 1
  for (int t = 0; t < NPAIR + 3 * (NWAVE - 1); t += 3) {
    pair_step(t + 0, 0, Ax0, Ax1, Am0, Am1, Bx0, Bx1, Bm0, Bm1);
    pair_step(t + 1, 1, Bx0, Bx1, Bm0, Bm1, Cx0, Cx1, Cm0, Cm1);
    pair_step(t + 2, 2, Cx0, Cx1, Cm0, Cm1, Ax0, Ax1, Am0, Am1);
    wg_barrier();
    px += 6 * NDIM;
    pm += 6 * NDIM;
    po += 6 * NDIM;
  }
  // all waves synced by the final group barrier; recs no longer used.
  // c2_0/oc2_0 now hold row-448 constants (prepped at s=223).

  // ---- bridge: row-448 constants + fu/S; reload rows 449..451 into
  // FULL-phase single-row slots (L2-hot, one-time). t8 already =
  // c2(448) * w8 from the last fast step. ----
  float fx0, fm0, fx1, fm1, fx2, fm2, fx3, fm3;
  {
    float m448 = mb[(size_t)448 * NDIM];
    fx1 = xb[(size_t)449 * NDIM];
    fm1 = mb[(size_t)449 * NDIM];
    fx2 = xb[(size_t)450 * NDIM];
    fm2 = mb[(size_t)450 * NDIM];
    fx3 = xb[(size_t)451 * NDIM];
    fm3 = mb[(size_t)451 * NDIM];
    fx0 = fx1;  // defined; overwritten at m=448 step
    fm0 = fm1;
    c2 = c2_0;
    oc2 = oc2_0;
    c1 = m448 - c2;
    float om = 1.0f - m448;
    fu = fmaxf(w8 - om, 0.0f);
    S = fu;
  }

  // ---- FULL row body: proven 2-barrier exchange (backward dep on S) ----
  auto row_full = [&](int m, float& WX, float& WM, const float& RX,
                      const float& RM) {
    const size_t nro = (size_t)((m + 4) & (NDIM - 1)) * NDIM;
    WX = xb[nro];
    WM = mb[nro];

    // local wave scans (chain head)
    float PS = prefix_inc(S);
    float PA = prefix_inc(t8);

    if (lane == 63) {
      ex_sa[w] = PA;  // wave-inclusive totals
      ex_S[w] = PS;
    }
    wg_barrier();  // bar1: publish scan totals

    float4 sl = *(const float4*)&ex_sa[0];
    float4 sh = *(const float4*)&ex_sa[4];
    float4 Sl = *(const float4*)&ex_S[0];
    float4 Sh = *(const float4*)&ex_S[4];
    float off_sa = 0.0f, off_S = 0.0f;
    if (w > 0) { off_sa += sl.x; off_S += Sl.x; }
    if (w > 1) { off_sa += sl.y; off_S += Sl.y; }
    if (w > 2) { off_sa += sl.z; off_S += Sl.z; }
    if (w > 3) { off_sa += sl.w; off_S += Sl.w; }
    if (w > 4) { off_sa += sh.x; off_S += Sh.x; }
    if (w > 5) { off_sa += sh.y; off_S += Sh.y; }
    if (w > 6) { off_sa += sh.z; off_S += Sh.z; }
    float Tg =
        ((Sl.x + Sl.y) + (Sl.z + Sl.w)) + ((Sh.x + Sh.y) + (Sh.z + Sh.w));

    float uin = fmaxf(1.0f - (off_sa + (PA - t8)), 0.0f);
    float R_ = (Tg - off_S) - PS;  // future mass strictly after this lane
    float nc1m = -c1 * R_;         // per-lane suf == 0 at 1 col/lane

    // branch prediction (1 cell)
    bool pW = w8 < uin;
    float aP = pW ? 1.0f : oc2;
    float bP = pW ? (-t8) : 0.0f;
    bool pL = (uin - R_) > 0.0f;
    if (pL) {
      aP -= c1;
      bP -= nc1m;
    }

    // wave affine scan
    float A = aP, Bv = bP;
    aff_scan(A, Bv);
    float Aex = wave_shr1(A, 1.0f);
    float Bex = wave_shr1(Bv, 0.0f);

    if (lane == 63) {
      ex_A[w] = A;  // wave-inclusive composition
      ex_B[w] = Bv;
    }
    wg_barrier();  // bar2: publish affine totals

    float4 Al = *(const float4*)&ex_A[0];
    float4 Ah = *(const float4*)&ex_A[4];
    float4 Bl = *(const float4*)&ex_B[0];
    float4 Bh = *(const float4*)&ex_B[4];
    float E = 1.0f;
    if (w > 0) E = fmaf(Al.x, E, Bl.x);
    if (w > 1) E = fmaf(Al.y, E, Bl.y);
    if (w > 2) E = fmaf(Al.z, E, Bl.z);
    if (w > 3) E = fmaf(Al.w, E, Bl.w);
    if (w > 4) E = fmaf(Ah.x, E, Bh.x);
    if (w > 5) E = fmaf(Ah.y, E, Bh.y);
    if (w > 6) E = fmaf(Ah.z, E, Bh.z);
    float e = fminf(fmaxf(fmaf(Aex, E, Bex), 0.0f), 1.0f);  // lane entry

    // row m+1 x-only prep (off-chain)
    float sg = __builtin_amdgcn_rcpf(1.0f + __expf(-RX));
    float c2n = RM * sg;
    float oc2n = 1.0f - c2n;
    float c1n = RM - c2n;
    float omn = 1.0f - RM;

    // TRUE-branch output
    float U = fminf(e, w8);
    float g = fmaxf(fmaf(c1, e, nc1m), 0.0f);
    float p = fmaf(c2, U, g);
    w8 -= p;
    ob[(size_t)m * NDIM] = p;

    // next row's scan inputs
    t8 = c2n * w8;
    fu = fmaxf(w8 - omn, 0.0f);
    S = fu;
    c2 = c2n;
    oc2 = oc2n;
    c1 = c1n;
  };

#pragma unroll 1
  for (int m = NFAST; m < NDIM; m += 4) {
    row_full(m + 0, fx0, fm0, fx1, fm1);
    row_full(m + 1, fx1, fm1, fx2, fm2);
    row_full(m + 2, fx2, fm2, fx3, fm3);
    row_full(m + 3, fx3, fm3, fx0, fm0);
  }
}

extern "C" void kernel_launch(void* const* d_in, const int* in_sizes, int n_in,
                              void* d_out, int out_size, void* d_ws,
                              size_t ws_size, hipStream_t stream) {
  const float* x = (const float*)d_in[0];
  const float* xmask = (const float*)d_in[1];
  float* out = (float*)d_out;
  (void)in_sizes;
  (void)n_in;
  (void)out_size;
  (void)d_ws;
  (void)ws_size;
  hipLaunchKernelGGL(sb_kernel, dim3(NBATCH), dim3(512), 0, stream, x, xmask,
                     out);
}

// Round 10
// 235.627 us; speedup vs baseline: 1.1629x; 1.0629x over previous
//
#include <hip/hip_runtime.h>

#define NBATCH 32
#define NDIM 512
#define NFAST 448
#define NQUAD 112
#define NWAVE 8

// ---- DPP cross-lane primitives ----
// Native DPP-arithmetic forms (gfx9 idiom): one instruction per scan
// stage. Invalid source lanes (no bound_ctrl => don't write) keep their
// value = scan identity. s_nop's cover the VALU-write -> DPP-read
// hazard (2 wait states) across the asm boundary.

// wave64 inclusive prefix sum (6 x v_add_f32_dpp)
__device__ __forceinline__ float prefix_inc(float x) {
  asm("s_nop 1\n\t"
      "v_add_f32_dpp %0, %0, %0 row_shr:1 row_mask:0xf bank_mask:0xf\n\t"
      "s_nop 1\n\t"
      "v_add_f32_dpp %0, %0, %0 row_shr:2 row_mask:0xf bank_mask:0xf\n\t"
      "s_nop 1\n\t"
      "v_add_f32_dpp %0, %0, %0 row_shr:4 row_mask:0xf bank_mask:0xf\n\t"
      "s_nop 1\n\t"
      "v_add_f32_dpp %0, %0, %0 row_shr:8 row_mask:0xf bank_mask:0xf\n\t"
      "s_nop 1\n\t"
      "v_add_f32_dpp %0, %0, %0 row_bcast:15 row_mask:0xa bank_mask:0xf\n\t"
      "s_nop 1\n\t"
      "v_add_f32_dpp %0, %0, %0 row_bcast:31 row_mask:0xc bank_mask:0xf\n\t"
      "s_nop 1"
      : "+v"(x));
  return x;
}

// TWO independent inclusive prefix sums, stages interleaved so each
// scan's 2-slot DPP hazard window is filled by the other's stage.
// Per-scan math and order identical to prefix_inc => bit-identical.
__device__ __forceinline__ void prefix_inc2(float& a, float& b) {
  asm("s_nop 1\n\t"
      "v_add_f32_dpp %0, %0, %0 row_shr:1 row_mask:0xf bank_mask:0xf\n\t"
      "v_add_f32_dpp %1, %1, %1 row_shr:1 row_mask:0xf bank_mask:0xf\n\t"
      "s_nop 0\n\t"
      "v_add_f32_dpp %0, %0, %0 row_shr:2 row_mask:0xf bank_mask:0xf\n\t"
      "v_add_f32_dpp %1, %1, %1 row_shr:2 row_mask:0xf bank_mask:0xf\n\t"
      "s_nop 0\n\t"
      "v_add_f32_dpp %0, %0, %0 row_shr:4 row_mask:0xf bank_mask:0xf\n\t"
      "v_add_f32_dpp %1, %1, %1 row_shr:4 row_mask:0xf bank_mask:0xf\n\t"
      "s_nop 0\n\t"
      "v_add_f32_dpp %0, %0, %0 row_shr:8 row_mask:0xf bank_mask:0xf\n\t"
      "v_add_f32_dpp %1, %1, %1 row_shr:8 row_mask:0xf bank_mask:0xf\n\t"
      "s_nop 0\n\t"
      "v_add_f32_dpp %0, %0, %0 row_bcast:15 row_mask:0xa bank_mask:0xf\n\t"
      "v_add_f32_dpp %1, %1, %1 row_bcast:15 row_mask:0xa bank_mask:0xf\n\t"
      "s_nop 0\n\t"
      "v_add_f32_dpp %0, %0, %0 row_bcast:31 row_mask:0xc bank_mask:0xf\n\t"
      "v_add_f32_dpp %1, %1, %1 row_bcast:31 row_mask:0xc bank_mask:0xf\n\t"
      "s_nop 1"
      : "+v"(a), "+v"(b));
}

// wave64 inclusive affine-composition scan: per stage
//   B += dpp(B) * A   (v_fmac, pre-update A == fmaf(A, Be, B))
//   A *= dpp(A)       (v_mul)
// Skipped invalid lanes == compose with identity (1,0).
__device__ __forceinline__ void aff_scan(float& A, float& B) {
  asm("s_nop 1\n\t"
      "v_fmac_f32_dpp %1, %1, %0 row_shr:1 row_mask:0xf bank_mask:0xf\n\t"
      "v_mul_f32_dpp  %0, %0, %0 row_shr:1 row_mask:0xf bank_mask:0xf\n\t"
      "s_nop 0\n\t"
      "v_fmac_f32_dpp %1, %1, %0 row_shr:2 row_mask:0xf bank_mask:0xf\n\t"
      "v_mul_f32_dpp  %0, %0, %0 row_shr:2 row_mask:0xf bank_mask:0xf\n\t"
      "s_nop 0\n\t"
      "v_fmac_f32_dpp %1, %1, %0 row_shr:4 row_mask:0xf bank_mask:0xf\n\t"
      "v_mul_f32_dpp  %0, %0, %0 row_shr:4 row_mask:0xf bank_mask:0xf\n\t"
      "s_nop 0\n\t"
      "v_fmac_f32_dpp %1, %1, %0 row_shr:8 row_mask:0xf bank_mask:0xf\n\t"
      "v_mul_f32_dpp  %0, %0, %0 row_shr:8 row_mask:0xf bank_mask:0xf\n\t"
      "s_nop 0\n\t"
      "v_fmac_f32_dpp %1, %1, %0 row_bcast:15 row_mask:0xa bank_mask:0xf\n\t"
      "v_mul_f32_dpp  %0, %0, %0 row_bcast:15 row_mask:0xa bank_mask:0xf\n\t"
      "s_nop 0\n\t"
      "v_fmac_f32_dpp %1, %1, %0 row_bcast:31 row_mask:0xc bank_mask:0xf\n\t"
      "v_mul_f32_dpp  %0, %0, %0 row_bcast:31 row_mask:0xc bank_mask:0xf\n\t"
      "s_nop 1"
      : "+v"(A), "+v"(B));
}

// shift one lane up (lane i gets lane i-1); lane 0 receives `fill`
__device__ __forceinline__ float wave_shr1(float x, float fill) {
  return __int_as_float(__builtin_amdgcn_update_dpp(
      __float_as_int(fill), __float_as_int(x), 0x138 /*wave_shr:1*/, 0xf, 0xf,
      false));
}

// Workgroup barrier WITHOUT the vmcnt(0) drain __syncthreads() emits.
__device__ __forceinline__ void wg_barrier() {
  asm volatile("s_waitcnt lgkmcnt(0)" ::: "memory");
  __builtin_amdgcn_s_barrier();
  asm volatile("" ::: "memory");
}

// R23: R22's systolic (PROVEN math, verbatim order) with FOUR rows per
// step to halve per-step fixed costs again (one LDS record-read window
// and one load batch per 4 rows; 63 barriers total). Wave w owns cols
// [64w,64w+64), lane owns 1 col; wave w does quad q (rows 4q..4q+3) at
// step t = q + 2w; one barrier per 2 quad-steps. A record written at
// step T is read at T+2; exactly one group barrier lies in (T, T+2].
// FULL rows (448+, backward suffix dep) keep the 2-barrier body with
// the two independent prefix scans interleaved (bit-identical math).
__global__ __launch_bounds__(512, 2)
void sb_kernel(const float* __restrict__ x, const float* __restrict__ xm,
               float* __restrict__ out) {
  const int tid = (int)threadIdx.x;
  const int lane = tid & 63;
  const int w = __builtin_amdgcn_readfirstlane(tid >> 6);  // wave id 0..7
  const int w2 = 2 * w;                                    // skew in steps
  const size_t base =
      (size_t)blockIdx.x * NDIM * NDIM + (size_t)(w * 64 + lane);
  const float* xb = x + base;
  const float* mb = xm + base;
  float* ob = out + base;

  __shared__ float4 recs[NFAST];              // rolling cum {A,B,cumPA,-}
  __shared__ alignas(16) float ex_sa[NWAVE];  // FULL-mode exchange
  __shared__ alignas(16) float ex_S[NWAVE];
  __shared__ alignas(16) float ex_A[NWAVE];
  __shared__ alignas(16) float ex_B[NWAVE];

  // per-lane state
  float w8, t8;  // stick remainder + current row's scan input
  float c2_0, oc2_0, c2_1, oc2_1, c2_2, oc2_2, c2_3, oc2_3;  // quad consts
  float c1, c2, oc2;  // FULL-phase per-row constants
  float fu = 0.0f, S = 0.0f;

  // ---- prologue: rows 0..3 direct (current quad constants); quad 1
  // (rows 4..7) -> slot B. Slot discipline (2 slots, each one QUAD):
  // at group step k (t = base+k), write quad q+2 into slot[k], prep
  // quad q+1 from slot[k^1]; load->prep distance = 1 quad-step. ----
  float X0 = xb[0], X1 = xb[NDIM], X2 = xb[2 * NDIM], X3 = xb[3 * NDIM];
  float M0 = mb[0], M1 = mb[NDIM], M2 = mb[2 * NDIM], M3 = mb[3 * NDIM];
  float Bx0 = xb[4 * NDIM], Bx1 = xb[5 * NDIM], Bx2 = xb[6 * NDIM],
        Bx3 = xb[7 * NDIM];
  float Bm0 = mb[4 * NDIM], Bm1 = mb[5 * NDIM], Bm2 = mb[6 * NDIM],
        Bm3 = mb[7 * NDIM];
  float Ax0 = Bx0, Ax1 = Bx1, Ax2 = Bx2, Ax3 = Bx3;  // slot A (dead init)
  float Am0 = Bm0, Am1 = Bm1, Am2 = Bm2, Am3 = Bm3;

  {  // prep rows 0..3 constants; row-0 scan input (w8 == 1)
    float s0 = __builtin_amdgcn_rcpf(1.0f + __expf(-X0));
    float s1 = __builtin_amdgcn_rcpf(1.0f + __expf(-X1));
    float s2 = __builtin_amdgcn_rcpf(1.0f + __expf(-X2));
    float s3 = __builtin_amdgcn_rcpf(1.0f + __expf(-X3));
    c2_0 = M0 * s0;
    oc2_0 = 1.0f - c2_0;
    c2_1 = M1 * s1;
    oc2_1 = 1.0f - c2_1;
    c2_2 = M2 * s2;
    oc2_2 = 1.0f - c2_2;
    c2_3 = M3 * s3;
    oc2_3 = 1.0f - c2_3;
    w8 = 1.0f;
    t8 = c2_0;
  }

  // running pointers (strength-reduced; advance unconditionally per
  // group; inactive waves never dereference). At wave w's first active
  // step (t = 2w, group base): load quad 2 (row 8) / store row 0.
  const float* px = xb + (long)(8 - 8 * w) * NDIM;
  const float* pm = mb + (long)(8 - 8 * w) * NDIM;
  float* po = ob - (long)(8 * w) * NDIM;

  // ---- one row of proven math (guess scan + affine scan) ----
  auto row_fast = [&](int m, const float4& r, float c2r, float oc2r,
                      float* pO) {
    float PA = prefix_inc(t8);
    float uin = fmaxf(1.0f - (r.z + (PA - t8)), 0.0f);
    bool pW = w8 < uin;
    float A = pW ? 1.0f : oc2r;
    float Bv = pW ? (-t8) : 0.0f;
    aff_scan(A, Bv);
    float Aex = wave_shr1(A, 1.0f);
    float Bex = wave_shr1(Bv, 0.0f);
    if (w < NWAVE - 1 && lane == 63)
      recs[m] = make_float4(A * r.x, fmaf(A, r.y, Bv), r.z + PA, 0.0f);
    float E = r.x + r.y;
    float e = fminf(fmaxf(fmaf(Aex, E, Bex), 0.0f), 1.0f);
    float p = c2r * fminf(e, w8);
    w8 -= p;
    *pO = p;
  };

  // ---- 4-row systolic step (barrier per 2 steps) ----
  auto quad_step = [&](int t, int k, float& WX0, float& WX1, float& WX2,
                       float& WX3, float& WM0, float& WM1, float& WM2,
                       float& WM3, const float& RX0, const float& RX1,
                       const float& RX2, const float& RX3, const float& RM0,
                       const float& RM1, const float& RM2, const float& RM3) {
    const int q = t - w2;
    if ((unsigned)q < (unsigned)NQUAD) {  // wave-uniform
      const int m = 4 * q;
      // read all 4 predecessor cum records together (one latency window;
      // published >= 2 steps ago, across >= 1 group barrier)
      float4 r0 = make_float4(1.0f, 0.0f, 0.0f, 0.0f);
      float4 r1 = r0, r2 = r0, r3 = r0;
      if (w > 0) {
        r0 = recs[m];
        r1 = recs[m + 1];
        r2 = recs[m + 2];
        r3 = recs[m + 3];
      }
      // issue next quad's global loads (quad q+2) into slot registers
      const float* pxk = px + (size_t)(4 * k) * NDIM;
      const float* pmk = pm + (size_t)(4 * k) * NDIM;
      WX0 = pxk[0];
      WX1 = pxk[NDIM];
      WX2 = pxk[2 * NDIM];
      WX3 = pxk[3 * NDIM];
      WM0 = pmk[0];
      WM1 = pmk[NDIM];
      WM2 = pmk[2 * NDIM];
      WM3 = pmk[3 * NDIM];

      // prep quad q+1 (data loaded 1 quad-step ago; off-chain)
      float s0 = __builtin_amdgcn_rcpf(1.0f + __expf(-RX0));
      float s1 = __builtin_amdgcn_rcpf(1.0f + __expf(-RX1));
      float s2 = __builtin_amdgcn_rcpf(1.0f + __expf(-RX2));
      float s3 = __builtin_amdgcn_rcpf(1.0f + __expf(-RX3));
      float c2n0 = RM0 * s0, oc2n0 = 1.0f - c2n0;
      float c2n1 = RM1 * s1, oc2n1 = 1.0f - c2n1;
      float c2n2 = RM2 * s2, oc2n2 = 1.0f - c2n2;
      float c2n3 = RM3 * s3, oc2n3 = 1.0f - c2n3;

      float* pok = po + (size_t)(4 * k) * NDIM;
      row_fast(m + 0, r0, c2_0, oc2_0, pok);
      t8 = c2_1 * w8;
      row_fast(m + 1, r1, c2_1, oc2_1, pok + NDIM);
      t8 = c2_2 * w8;
      row_fast(m + 2, r2, c2_2, oc2_2, pok + 2 * NDIM);
      t8 = c2_3 * w8;
      row_fast(m + 3, r3, c2_3, oc2_3, pok + 3 * NDIM);
      // next quad's scan input + constants
      t8 = c2n0 * w8;
      c2_0 = c2n0;
      oc2_0 = oc2n0;
      c2_1 = c2n1;
      oc2_1 = oc2n1;
      c2_2 = c2n2;
      oc2_2 = oc2n2;
      c2_3 = c2n3;
      oc2_3 = oc2n3;
    }
  };

  // fast phase: steps t = 0 .. 125 (wave w active for t in [2w, 2w+112));
  // one barrier per 2-step group (8 rows).
#pragma unroll 1
  for (int t = 0; t < NQUAD + 2 * (NWAVE - 1); t += 2) {
    quad_step(t + 0, 0, Ax0, Ax1, Ax2, Ax3, Am0, Am1, Am2, Am3, Bx0, Bx1, Bx2,
              Bx3, Bm0, Bm1, Bm2, Bm3);
    quad_step(t + 1, 1, Bx0, Bx1, Bx2, Bx3, Bm0, Bm1, Bm2, Bm3, Ax0, Ax1, Ax2,
              Ax3, Am0, Am1, Am2, Am3);
    wg_barrier();
    px += 8 * NDIM;
    pm += 8 * NDIM;
    po += 8 * NDIM;
  }
  // all waves synced by the final group barrier; recs no longer used.
  // c2_0..3 now hold rows 448..451 constants (prepped at q=111);
  // t8 = c2(448) * w8 from the last fast step's tail.

  // ---- bridge: row-448 constants + fu/S; reload rows 449..451 into
  // FULL-phase single-row slots (L2-hot, one-time). ----
  float fx0, fm0, fx1, fm1, fx2, fm2, fx3, fm3;
  {
    float m448 = mb[(size_t)448 * NDIM];
    fx1 = xb[(size_t)449 * NDIM];
    fm1 = mb[(size_t)449 * NDIM];
    fx2 = xb[(size_t)450 * NDIM];
    fm2 = mb[(size_t)450 * NDIM];
    fx3 = xb[(size_t)451 * NDIM];
    fm3 = mb[(size_t)451 * NDIM];
    fx0 = fx1;  // defined; overwritten at m=448 step
    fm0 = fm1;
    c2 = c2_0;
    oc2 = oc2_0;
    c1 = m448 - c2;
    float om = 1.0f - m448;
    fu = fmaxf(w8 - om, 0.0f);
    S = fu;
  }

  // ---- FULL row body: proven 2-barrier exchange (backward dep on S) ----
  auto row_full = [&](int m, float& WX, float& WM, const float& RX,
                      const float& RM) {
    const size_t nro = (size_t)((m + 4) & (NDIM - 1)) * NDIM;
    WX = xb[nro];
    WM = mb[nro];

    // local wave scans (chain head); independent scans interleaved
    float PS = S, PA = t8;
    prefix_inc2(PS, PA);

    if (lane == 63) {
      ex_sa[w] = PA;  // wave-inclusive totals
      ex_S[w] = PS;
    }
    wg_barrier();  // bar1: publish scan totals

    float4 sl = *(const float4*)&ex_sa[0];
    float4 sh = *(const float4*)&ex_sa[4];
    float4 Sl = *(const float4*)&ex_S[0];
    float4 Sh = *(const float4*)&ex_S[4];
    float off_sa = 0.0f, off_S = 0.0f;
    if (w > 0) { off_sa += sl.x; off_S += Sl.x; }
    if (w > 1) { off_sa += sl.y; off_S += Sl.y; }
    if (w > 2) { off_sa += sl.z; off_S += Sl.z; }
    if (w > 3) { off_sa += sl.w; off_S += Sl.w; }
    if (w > 4) { off_sa += sh.x; off_S += Sh.x; }
    if (w > 5) { off_sa += sh.y; off_S += Sh.y; }
    if (w > 6) { off_sa += sh.z; off_S += Sh.z; }
    float Tg =
        ((Sl.x + Sl.y) + (Sl.z + Sl.w)) + ((Sh.x + Sh.y) + (Sh.z + Sh.w));

    float uin = fmaxf(1.0f - (off_sa + (PA - t8)), 0.0f);
    float R_ = (Tg - off_S) - PS;  // future mass strictly after this lane
    float nc1m = -c1 * R_;         // per-lane suf == 0 at 1 col/lane

    // branch prediction (1 cell)
    bool pW = w8 < uin;
    float aP = pW ? 1.0f : oc2;
    float bP = pW ? (-t8) : 0.0f;
    bool pL = (uin - R_) > 0.0f;
    if (pL) {
      aP -= c1;
      bP -= nc1m;
    }

    // wave affine scan
    float A = aP, Bv = bP;
    aff_scan(A, Bv);
    float Aex = wave_shr1(A, 1.0f);
    float Bex = wave_shr1(Bv, 0.0f);

    if (lane == 63) {
      ex_A[w] = A;  // wave-inclusive composition
      ex_B[w] = Bv;
    }
    wg_barrier();  // bar2: publish affine totals

    float4 Al = *(const float4*)&ex_A[0];
    float4 Ah = *(const float4*)&ex_A[4];
    float4 Bl = *(const float4*)&ex_B[0];
    float4 Bh = *(const float4*)&ex_B[4];
    float E = 1.0f;
    if (w > 0) E = fmaf(Al.x, E, Bl.x);
    if (w > 1) E = fmaf(Al.y, E, Bl.y);
    if (w > 2) E = fmaf(Al.z, E, Bl.z);
    if (w > 3) E = fmaf(Al.w, E, Bl.w);
    if (w > 4) E = fmaf(Ah.x, E, Bh.x);
    if (w > 5) E = fmaf(Ah.y, E, Bh.y);
    if (w > 6) E = fmaf(Ah.z, E, Bh.z);
    float e = fminf(fmaxf(fmaf(Aex, E, Bex), 0.0f), 1.0f);  // lane entry

    // row m+1 x-only prep (off-chain)
    float sg = __builtin_amdgcn_rcpf(1.0f + __expf(-RX));
    float c2n = RM * sg;
    float oc2n = 1.0f - c2n;
    float c1n = RM - c2n;
    float omn = 1.0f - RM;

    // TRUE-branch output
    float U = fminf(e, w8);
    float g = fmaxf(fmaf(c1, e, nc1m), 0.0f);
    float p = fmaf(c2, U, g);
    w8 -= p;
    ob[(size_t)m * NDIM] = p;

    // next row's scan inputs
    t8 = c2n * w8;
    fu = fmaxf(w8 - omn, 0.0f);
    S = fu;
    c2 = c2n;
    oc2 = oc2n;
    c1 = c1n;
  };

#pragma unroll 1
  for (int m = NFAST; m < NDIM; m += 4) {
    row_full(m + 0, fx0, fm0, fx1, fm1);
    row_full(m + 1, fx1, fm1, fx2, fm2);
    row_full(m + 2, fx2, fm2, fx3, fm3);
    row_full(m + 3, fx3, fm3, fx0, fm0);
  }
}

extern "C" void kernel_launch(void* const* d_in, const int* in_sizes, int n_in,
                              void* d_out, int out_size, void* d_ws,
                              size_t ws_size, hipStream_t stream) {
  const float* x = (const float*)d_in[0];
  const float* xmask = (const float*)d_in[1];
  float* out = (float*)d_out;
  (void)in_sizes;
  (void)n_in;
  (void)out_size;
  (void)d_ws;
  (void)ws_size;
  hipLaunchKernelGGL(sb_kernel, dim3(NBATCH), dim3(512), 0, stream, x, xmask,
                     out);
}